// Round 4
// baseline (971.618 us; speedup 1.0000x reference)
//
#include <hip/hip_runtime.h>
#include <hip/hip_bf16.h>
#include <math.h>

#define Hdim 1024
#define Fdim 2
#define VOCAB 32000
#define Bdim 64
#define Ldim 1024
#define GRU_IN 2052   // 2*(H+F)

// ---------------------------------------------------------------------------
// Kernel 1: build GRU input x[b][0:1024]=emb[seq[b]], [1024:1026]=feature[b],
//           [1026:2052]=pos_emb[positions[b]]
// ---------------------------------------------------------------------------
__global__ void build_x(const int* __restrict__ seq, const int* __restrict__ pos,
                        const float* __restrict__ feat, const float* __restrict__ emb,
                        const float* __restrict__ pemb, float* __restrict__ x) {
    int b = blockIdx.x;
    int t = threadIdx.x;
    int idx = seq[b];
    int p = pos[b];
    float* xr = x + (size_t)b * GRU_IN;
    const float* er = emb + (size_t)idx * Hdim;
    for (int i = t; i < Hdim; i += 256) xr[i] = er[i];
    if (t < Fdim) xr[Hdim + t] = feat[b * Fdim + t];
    const float* pr = pemb + (size_t)p * (Hdim + Fdim);
    for (int i = t; i < Hdim + Fdim; i += 256) xr[Hdim + Fdim + i] = pr[i];
}

// ---------------------------------------------------------------------------
// Generic skinny GEMM: C[64][N] = act(X[64][K] @ W[N][K]^T + bias[N])
// grid.x = N/64, block = 256. K % 4 == 0 required.
// LDS layout [kg][row][float4] -> 2-way read conflicts (free).
// ---------------------------------------------------------------------------
template<int ACT>  // 0 = none, 1 = tanh
__global__ void gemm_xwt(const float* __restrict__ X, const float* __restrict__ W,
                         const float* __restrict__ bias, float* __restrict__ C,
                         int N, int K, int ldc) {
    __shared__ float4 Xl[8][64];
    __shared__ float4 Wl[8][64];
    int t  = threadIdx.x;
    int tb = t & 15;          // batch group
    int tj = t >> 4;          // j group
    int j0 = blockIdx.x * 64;
    int r0 = t >> 3;          // staging row 0..31
    int kg = t & 7;           // staging k-group

    float acc[4][4];
#pragma unroll
    for (int a = 0; a < 4; ++a)
#pragma unroll
        for (int c = 0; c < 4; ++c) acc[a][c] = 0.f;

    int nk = (K + 31) >> 5;
    for (int kc = 0; kc < nk; ++kc) {
        int k = (kc << 5) + (kg << 2);
        float4 z = make_float4(0.f, 0.f, 0.f, 0.f);
        bool ok = (k < K);
        float4 xv  = ok ? *(const float4*)(X + (size_t)r0 * K + k) : z;
        float4 xv2 = ok ? *(const float4*)(X + (size_t)(r0 + 32) * K + k) : z;
        float4 wv  = ok ? *(const float4*)(W + (size_t)(j0 + r0) * K + k) : z;
        float4 wv2 = ok ? *(const float4*)(W + (size_t)(j0 + r0 + 32) * K + k) : z;
        __syncthreads();
        Xl[kg][r0] = xv;  Xl[kg][r0 + 32] = xv2;
        Wl[kg][r0] = wv;  Wl[kg][r0 + 32] = wv2;
        __syncthreads();

#pragma unroll
        for (int g = 0; g < 8; ++g) {
            float4 xr[4], wr[4];
#pragma unroll
            for (int bb = 0; bb < 4; ++bb) xr[bb] = Xl[g][tb + 16 * bb];
#pragma unroll
            for (int jj = 0; jj < 4; ++jj) wr[jj] = Wl[g][tj + 16 * jj];
#pragma unroll
            for (int bb = 0; bb < 4; ++bb)
#pragma unroll
                for (int jj = 0; jj < 4; ++jj) {
                    acc[bb][jj] += xr[bb].x * wr[jj].x;
                    acc[bb][jj] += xr[bb].y * wr[jj].y;
                    acc[bb][jj] += xr[bb].z * wr[jj].z;
                    acc[bb][jj] += xr[bb].w * wr[jj].w;
                }
        }
    }

#pragma unroll
    for (int bb = 0; bb < 4; ++bb)
#pragma unroll
        for (int jj = 0; jj < 4; ++jj) {
            int b = tb + 16 * bb;
            int j = j0 + tj + 16 * jj;
            float v = acc[bb][jj] + bias[j];
            if (ACT == 1) v = tanhf(v);
            C[(size_t)b * ldc + j] = v;
        }
}

// ---------------------------------------------------------------------------
// GRU gate combine: h = (1-z)*n + z*h0, write h into hc[:,0:1024] and d_out h
// ---------------------------------------------------------------------------
__global__ void gru_gates(const float* __restrict__ gx, const float* __restrict__ gh,
                          const float* __restrict__ h0, float* __restrict__ hc,
                          float* __restrict__ outh) {
    int idx = blockIdx.x * 256 + threadIdx.x;   // 65536
    int b = idx >> 10, i = idx & 1023;
    const float* gxb = gx + (size_t)b * 3072;
    const float* ghb = gh + (size_t)b * 3072;
    float xr = gxb[i],        hr = ghb[i];
    float xz = gxb[1024 + i], hz = ghb[1024 + i];
    float xn = gxb[2048 + i], hn = ghb[2048 + i];
    float r = 1.f / (1.f + __expf(-(xr + hr)));
    float z = 1.f / (1.f + __expf(-(xz + hz)));
    float n = tanhf(xn + r * hn);
    float h = (1.f - z) * n + z * h0[(size_t)b * 1024 + i];
    hc[(size_t)b * 2048 + i] = h;
    outh[(size_t)b * 1024 + i] = h;
}

// ---------------------------------------------------------------------------
// Online-softmax attention pass. grid = (16 chunks, 64 b), block 256 (4 waves).
// Each wave processes 16 rows of enc[l][b][:], keeping running (m, s, ctx).
// Writes raw energies to e_ws and per-(b,chunk) partial (M, S, ctx[1024]).
// ---------------------------------------------------------------------------
__global__ void attn_pass(const float* __restrict__ enc, const float* __restrict__ hc,
                          float* __restrict__ e_ws, float* __restrict__ part) {
    int c = blockIdx.x, b = blockIdx.y;
    int t = threadIdx.x;
    int lane = t & 63, w = t >> 6;

    const float4* enc4 = (const float4*)enc;
    const float4* h4 = (const float4*)hc + (size_t)b * 512;   // row stride 2048 floats

    float4 hreg[4];
#pragma unroll
    for (int it = 0; it < 4; ++it) hreg[it] = h4[it * 64 + lane];

    float m = -INFINITY, s = 0.f;
    float4 ctx[4];
#pragma unroll
    for (int it = 0; it < 4; ++it) ctx[it] = make_float4(0.f, 0.f, 0.f, 0.f);

    int lbase = c * 64 + w * 16;
    for (int i = 0; i < 16; ++i) {
        int l = lbase + i;
        const float4* row = enc4 + ((size_t)l * 64 + b) * 256;
        float4 v[4];
        float ep = 0.f;
#pragma unroll
        for (int it = 0; it < 4; ++it) {
            v[it] = row[it * 64 + lane];
            ep += v[it].x * hreg[it].x + v[it].y * hreg[it].y +
                  v[it].z * hreg[it].z + v[it].w * hreg[it].w;
        }
#pragma unroll
        for (int off = 32; off > 0; off >>= 1) ep += __shfl_xor(ep, off);
        if (lane == 0) e_ws[(size_t)b * Ldim + l] = ep;

        float mn = fmaxf(m, ep);
        float corr = __expf(m - mn);     // 0 when m = -inf
        float p = __expf(ep - mn);
        s = s * corr + p;
#pragma unroll
        for (int it = 0; it < 4; ++it) {
            ctx[it].x = ctx[it].x * corr + v[it].x * p;
            ctx[it].y = ctx[it].y * corr + v[it].y * p;
            ctx[it].z = ctx[it].z * corr + v[it].z * p;
            ctx[it].w = ctx[it].w * corr + v[it].w * p;
        }
        m = mn;
    }

    // cross-wave merge
    __shared__ float4 csh[4][256];
    __shared__ float msh[4][2];
#pragma unroll
    for (int it = 0; it < 4; ++it) csh[w][it * 64 + lane] = ctx[it];
    if (lane == 0) { msh[w][0] = m; msh[w][1] = s; }
    __syncthreads();

    float M = fmaxf(fmaxf(msh[0][0], msh[1][0]), fmaxf(msh[2][0], msh[3][0]));
    float wgt[4], S = 0.f;
#pragma unroll
    for (int ww = 0; ww < 4; ++ww) {
        wgt[ww] = __expf(msh[ww][0] - M);
        S += msh[ww][1] * wgt[ww];
    }
    float4 sum = make_float4(0.f, 0.f, 0.f, 0.f);
#pragma unroll
    for (int ww = 0; ww < 4; ++ww) {
        float4 cv = csh[ww][t];
        sum.x += cv.x * wgt[ww]; sum.y += cv.y * wgt[ww];
        sum.z += cv.z * wgt[ww]; sum.w += cv.w * wgt[ww];
    }
    float* P = part + (size_t)(b * 16 + c) * 1032;
    if (t == 0) { P[0] = M; P[1] = S; }
    *(float4*)(P + 8 + t * 4) = sum;
}

// ---------------------------------------------------------------------------
// Merge 16 chunk-partials per b -> context into hc[:,1024:2048]; write attn out.
// ---------------------------------------------------------------------------
__global__ void attn_merge(const float* __restrict__ part, const float* __restrict__ e_ws,
                           float* __restrict__ hc, float* __restrict__ outp) {
    int b = blockIdx.x;
    int t = threadIdx.x;
    const float* Pb = part + (size_t)b * 16 * 1032;

    float Mc[16], Sc[16];
    float M = -INFINITY;
#pragma unroll
    for (int c = 0; c < 16; ++c) {
        Mc[c] = Pb[c * 1032];
        Sc[c] = Pb[c * 1032 + 1];
        M = fmaxf(M, Mc[c]);
    }
    float wg[16], S = 0.f;
#pragma unroll
    for (int c = 0; c < 16; ++c) {
        wg[c] = __expf(Mc[c] - M);
        S += Sc[c] * wg[c];
    }
    float inv = 1.f / S;

    float4 sum = make_float4(0.f, 0.f, 0.f, 0.f);
#pragma unroll
    for (int c = 0; c < 16; ++c) {
        float4 cv = *(const float4*)(Pb + c * 1032 + 8 + t * 4);
        sum.x += cv.x * wg[c]; sum.y += cv.y * wg[c];
        sum.z += cv.z * wg[c]; sum.w += cv.w * wg[c];
    }
    sum.x *= inv; sum.y *= inv; sum.z *= inv; sum.w *= inv;
    *(float4*)(hc + (size_t)b * 2048 + 1024 + t * 4) = sum;

    float* attn = outp + (size_t)Bdim * VOCAB + (size_t)Bdim * Hdim + (size_t)b * Ldim;
    for (int l = t; l < Ldim; l += 256)
        attn[l] = __expf(e_ws[(size_t)b * Ldim + l] - M) * inv;
}

// ---------------------------------------------------------------------------
extern "C" void kernel_launch(void* const* d_in, const int* in_sizes, int n_in,
                              void* d_out, int out_size, void* d_ws, size_t ws_size,
                              hipStream_t stream) {
    const int*   seq  = (const int*)d_in[0];
    const float* h0   = (const float*)d_in[1];
    const float* enc  = (const float*)d_in[2];
    const int*   pos  = (const int*)d_in[3];
    const float* feat = (const float*)d_in[4];
    const float* emb  = (const float*)d_in[5];
    const float* pemb = (const float*)d_in[6];
    const float* W_ih = (const float*)d_in[7];
    const float* W_hh = (const float*)d_in[8];
    const float* b_ih = (const float*)d_in[9];
    const float* b_hh = (const float*)d_in[10];
    const float* W_c  = (const float*)d_in[11];
    const float* b_c  = (const float*)d_in[12];
    const float* W_o  = (const float*)d_in[13];
    const float* b_o  = (const float*)d_in[14];

    float* out = (float*)d_out;
    float* ws  = (float*)d_ws;

    float* x_ws   = ws;                 // 64*2052        = 131328
    float* gx_ws  = ws + 131328;        // 64*3072        = 196608
    float* gh_ws  = ws + 327936;        // 64*3072        = 196608
    float* hc_ws  = ws + 524544;        // 64*2048 (h|ctx)= 131072
    float* e_ws   = ws + 655616;        // 64*1024        = 65536
    float* part   = ws + 721152;        // 64*16*1032     = 1056768
    float* cat_ws = ws + 1777920;       // 64*1024        = 65536

    build_x<<<64, 256, 0, stream>>>(seq, pos, feat, emb, pemb, x_ws);
    gemm_xwt<0><<<48, 256, 0, stream>>>(x_ws, W_ih, b_ih, gx_ws, 3072, GRU_IN, 3072);
    gemm_xwt<0><<<48, 256, 0, stream>>>(h0, W_hh, b_hh, gh_ws, 3072, 1024, 3072);
    gru_gates<<<256, 256, 0, stream>>>(gx_ws, gh_ws, h0, hc_ws, out + (size_t)Bdim * VOCAB);
    attn_pass<<<dim3(16, 64), 256, 0, stream>>>(enc, hc_ws, e_ws, part);
    attn_merge<<<64, 256, 0, stream>>>(part, e_ws, hc_ws, out);
    gemm_xwt<1><<<16, 256, 0, stream>>>(hc_ws, W_c, b_c, cat_ws, 1024, 2048, 1024);
    gemm_xwt<0><<<500, 256, 0, stream>>>(cat_ws, W_o, b_o, out, VOCAB, 1024, VOCAB);
}

// Round 8
// 683.320 us; speedup vs baseline: 1.4219x; 1.4219x over previous
//
#include <hip/hip_runtime.h>
#include <hip/hip_bf16.h>
#include <math.h>

#define Hdim 1024
#define Fdim 2
#define VOCAB 32000
#define Bdim 64
#define Ldim 1024
#define GRU_IN 2052   // 2*(H+F)

// ---------------------------------------------------------------------------
// build GRU input x[b] = [emb[seq[b]] | feature[b] | pos_emb[positions[b]]]
// ---------------------------------------------------------------------------
__global__ void build_x(const int* __restrict__ seq, const int* __restrict__ pos,
                        const float* __restrict__ feat, const float* __restrict__ emb,
                        const float* __restrict__ pemb, float* __restrict__ x) {
    int b = blockIdx.x;
    int t = threadIdx.x;
    int idx = seq[b];
    int p = pos[b];
    float* xr = x + (size_t)b * GRU_IN;
    const float* er = emb + (size_t)idx * Hdim;
    for (int i = t; i < Hdim; i += 256) xr[i] = er[i];
    if (t < Fdim) xr[Hdim + t] = feat[b * Fdim + t];
    const float* pr = pemb + (size_t)p * (Hdim + Fdim);
    for (int i = t; i < Hdim + Fdim; i += 256) xr[Hdim + Fdim + i] = pr[i];
}

// ---------------------------------------------------------------------------
// Skinny GEMM, K-sliced: C_slice[64][N] = X[64][K_slice] @ W[N][K_slice]^T
// grid = (N/64, nSlices), block 256. Each block owns kc in [kc0,kc1).
// Register-prefetch double buffering: next K-tile's global loads issue
// right after the LDS-visible barrier and are consumed next iteration.
// BIAS/ACT applied only by full-K (nSlices==1) callers.
// ---------------------------------------------------------------------------
template<int ACT, int BIAS>  // ACT: 0 none, 1 tanh
__launch_bounds__(256)
__global__ void gemm_bt(const float* __restrict__ X, const float* __restrict__ W,
                        const float* __restrict__ bias, float* __restrict__ C,
                        int N, int K, int ldc, int nkPer) {
    __shared__ float4 Xl[8][64];
    __shared__ float4 Wl[8][64];
    int t  = threadIdx.x;
    int tb = t & 15;          // batch group
    int tj = t >> 4;          // j group
    int j0 = blockIdx.x * 64;
    int r0 = t >> 3;          // staging row 0..31
    int kg = t & 7;           // staging k-group
    int nkTotal = (K + 31) >> 5;
    int kc0 = blockIdx.y * nkPer;
    int kc1 = min(nkTotal, kc0 + nkPer);
    float* Cs = C + (size_t)blockIdx.y * 64 * ldc;

    float acc[4][4];
#pragma unroll
    for (int a = 0; a < 4; ++a)
#pragma unroll
        for (int c = 0; c < 4; ++c) acc[a][c] = 0.f;

    float4 z = make_float4(0.f, 0.f, 0.f, 0.f);
    float4 xv = z, xv2 = z, wv = z, wv2 = z;
    {   // prefetch first tile
        int k = (kc0 << 5) + (kg << 2);
        bool ok = (k < K);
        if (ok) {
            xv  = *(const float4*)(X + (size_t)r0 * K + k);
            xv2 = *(const float4*)(X + (size_t)(r0 + 32) * K + k);
            wv  = *(const float4*)(W + (size_t)(j0 + r0) * K + k);
            wv2 = *(const float4*)(W + (size_t)(j0 + r0 + 32) * K + k);
        }
    }

    for (int kc = kc0; kc < kc1; ++kc) {
        __syncthreads();   // previous compute done -> LDS overwritable
        Xl[kg][r0] = xv;  Xl[kg][r0 + 32] = xv2;
        Wl[kg][r0] = wv;  Wl[kg][r0 + 32] = wv2;
        __syncthreads();   // LDS visible

        if (kc + 1 < kc1) {   // issue next tile's loads; land during compute
            int k = ((kc + 1) << 5) + (kg << 2);
            bool ok = (k < K);
            xv = z; xv2 = z; wv = z; wv2 = z;
            if (ok) {
                xv  = *(const float4*)(X + (size_t)r0 * K + k);
                xv2 = *(const float4*)(X + (size_t)(r0 + 32) * K + k);
                wv  = *(const float4*)(W + (size_t)(j0 + r0) * K + k);
                wv2 = *(const float4*)(W + (size_t)(j0 + r0 + 32) * K + k);
            }
        }

#pragma unroll
        for (int g = 0; g < 8; ++g) {
            float4 xr[4], wr[4];
#pragma unroll
            for (int bb = 0; bb < 4; ++bb) xr[bb] = Xl[g][tb + 16 * bb];
#pragma unroll
            for (int jj = 0; jj < 4; ++jj) wr[jj] = Wl[g][tj + 16 * jj];
#pragma unroll
            for (int bb = 0; bb < 4; ++bb)
#pragma unroll
                for (int jj = 0; jj < 4; ++jj) {
                    acc[bb][jj] += xr[bb].x * wr[jj].x;
                    acc[bb][jj] += xr[bb].y * wr[jj].y;
                    acc[bb][jj] += xr[bb].z * wr[jj].z;
                    acc[bb][jj] += xr[bb].w * wr[jj].w;
                }
        }
    }

#pragma unroll
    for (int bb = 0; bb < 4; ++bb)
#pragma unroll
        for (int jj = 0; jj < 4; ++jj) {
            int b = tb + 16 * bb;
            int j = j0 + tj + 16 * jj;
            float v = acc[bb][jj];
            if (BIAS) v += bias[j];
            if (ACT == 1) v = tanhf(v);
            Cs[(size_t)b * ldc + j] = v;
        }
}

// ---------------------------------------------------------------------------
// GRU gate combine over 4 K-slices each of gx/gh partials.
// h = (1-z)*n + z*h0 -> hc[:,0:1024] and d_out h
// ---------------------------------------------------------------------------
__global__ void gru_gates(const float* __restrict__ gxp, const float* __restrict__ ghp,
                          const float* __restrict__ b_ih, const float* __restrict__ b_hh,
                          const float* __restrict__ h0, float* __restrict__ hc,
                          float* __restrict__ outh) {
    int idx = blockIdx.x * 256 + threadIdx.x;   // 65536
    int b = idx >> 10, i = idx & 1023;
    float xr = b_ih[i], xz = b_ih[1024 + i], xn = b_ih[2048 + i];
    float hr = b_hh[i], hz = b_hh[1024 + i], hn = b_hh[2048 + i];
#pragma unroll
    for (int s = 0; s < 4; ++s) {
        const float* gx = gxp + ((size_t)s * 64 + b) * 3072;
        const float* gh = ghp + ((size_t)s * 64 + b) * 3072;
        xr += gx[i]; xz += gx[1024 + i]; xn += gx[2048 + i];
        hr += gh[i]; hz += gh[1024 + i]; hn += gh[2048 + i];
    }
    float r = 1.f / (1.f + __expf(-(xr + hr)));
    float zz = 1.f / (1.f + __expf(-(xz + hz)));
    float n = tanhf(xn + r * hn);
    float h = (1.f - zz) * n + zz * h0[(size_t)b * 1024 + i];
    hc[(size_t)b * 2048 + i] = h;
    outh[(size_t)b * 1024 + i] = h;
}

// ---------------------------------------------------------------------------
// Online-softmax attention pass. grid = (16 chunks, 64 b), block 256 (4 waves).
// ---------------------------------------------------------------------------
__global__ void attn_pass(const float* __restrict__ enc, const float* __restrict__ hc,
                          float* __restrict__ e_ws, float* __restrict__ part) {
    int c = blockIdx.x, b = blockIdx.y;
    int t = threadIdx.x;
    int lane = t & 63, w = t >> 6;

    const float4* enc4 = (const float4*)enc;
    const float4* h4 = (const float4*)hc + (size_t)b * 512;   // row stride 2048 floats

    float4 hreg[4];
#pragma unroll
    for (int it = 0; it < 4; ++it) hreg[it] = h4[it * 64 + lane];

    float m = -INFINITY, s = 0.f;
    float4 ctx[4];
#pragma unroll
    for (int it = 0; it < 4; ++it) ctx[it] = make_float4(0.f, 0.f, 0.f, 0.f);

    int lbase = c * 64 + w * 16;
    for (int i = 0; i < 16; ++i) {
        int l = lbase + i;
        const float4* row = enc4 + ((size_t)l * 64 + b) * 256;
        float4 v[4];
        float ep = 0.f;
#pragma unroll
        for (int it = 0; it < 4; ++it) {
            v[it] = row[it * 64 + lane];
            ep += v[it].x * hreg[it].x + v[it].y * hreg[it].y +
                  v[it].z * hreg[it].z + v[it].w * hreg[it].w;
        }
#pragma unroll
        for (int off = 32; off > 0; off >>= 1) ep += __shfl_xor(ep, off);
        if (lane == 0) e_ws[(size_t)b * Ldim + l] = ep;

        float mn = fmaxf(m, ep);
        float corr = __expf(m - mn);     // 0 when m = -inf
        float p = __expf(ep - mn);
        s = s * corr + p;
#pragma unroll
        for (int it = 0; it < 4; ++it) {
            ctx[it].x = ctx[it].x * corr + v[it].x * p;
            ctx[it].y = ctx[it].y * corr + v[it].y * p;
            ctx[it].z = ctx[it].z * corr + v[it].z * p;
            ctx[it].w = ctx[it].w * corr + v[it].w * p;
        }
        m = mn;
    }

    // cross-wave merge
    __shared__ float4 csh[4][256];
    __shared__ float msh[4][2];
#pragma unroll
    for (int it = 0; it < 4; ++it) csh[w][it * 64 + lane] = ctx[it];
    if (lane == 0) { msh[w][0] = m; msh[w][1] = s; }
    __syncthreads();

    float M = fmaxf(fmaxf(msh[0][0], msh[1][0]), fmaxf(msh[2][0], msh[3][0]));
    float wgt[4], S = 0.f;
#pragma unroll
    for (int ww = 0; ww < 4; ++ww) {
        wgt[ww] = __expf(msh[ww][0] - M);
        S += msh[ww][1] * wgt[ww];
    }
    float4 sum = make_float4(0.f, 0.f, 0.f, 0.f);
#pragma unroll
    for (int ww = 0; ww < 4; ++ww) {
        float4 cv = csh[ww][t];
        sum.x += cv.x * wgt[ww]; sum.y += cv.y * wgt[ww];
        sum.z += cv.z * wgt[ww]; sum.w += cv.w * wgt[ww];
    }
    float* P = part + (size_t)(b * 16 + c) * 1032;
    if (t == 0) { P[0] = M; P[1] = S; }
    *(float4*)(P + 8 + t * 4) = sum;
}

// ---------------------------------------------------------------------------
// Merge 16 chunk-partials per b -> context into hc[:,1024:2048]; attn out.
// ---------------------------------------------------------------------------
__global__ void attn_merge(const float* __restrict__ part, const float* __restrict__ e_ws,
                           float* __restrict__ hc, float* __restrict__ outp) {
    int b = blockIdx.x;
    int t = threadIdx.x;
    const float* Pb = part + (size_t)b * 16 * 1032;

    float Mc[16], Sc[16];
    float M = -INFINITY;
#pragma unroll
    for (int c = 0; c < 16; ++c) {
        Mc[c] = Pb[c * 1032];
        Sc[c] = Pb[c * 1032 + 1];
        M = fmaxf(M, Mc[c]);
    }
    float wg[16], S = 0.f;
#pragma unroll
    for (int c = 0; c < 16; ++c) {
        wg[c] = __expf(Mc[c] - M);
        S += Sc[c] * wg[c];
    }
    float inv = 1.f / S;

    float4 sum = make_float4(0.f, 0.f, 0.f, 0.f);
#pragma unroll
    for (int c = 0; c < 16; ++c) {
        float4 cv = *(const float4*)(Pb + c * 1032 + 8 + t * 4);
        sum.x += cv.x * wg[c]; sum.y += cv.y * wg[c];
        sum.z += cv.z * wg[c]; sum.w += cv.w * wg[c];
    }
    sum.x *= inv; sum.y *= inv; sum.z *= inv; sum.w *= inv;
    *(float4*)(hc + (size_t)b * 2048 + 1024 + t * 4) = sum;

    float* attn = outp + (size_t)Bdim * VOCAB + (size_t)Bdim * Hdim + (size_t)b * Ldim;
    for (int l = t; l < Ldim; l += 256)
        attn[l] = __expf(e_ws[(size_t)b * Ldim + l] - M) * inv;
}

// ---------------------------------------------------------------------------
// Reduce 8 K-slices of the W_c GEMM + bias + tanh -> cat_ws[64][1024]
// ---------------------------------------------------------------------------
__global__ void cat_combine(const float* __restrict__ cp, const float* __restrict__ b_c,
                            float* __restrict__ catw) {
    int idx = blockIdx.x * 256 + threadIdx.x;   // 65536
    int b = idx >> 10, j = idx & 1023;
    float v = b_c[j];
#pragma unroll
    for (int s = 0; s < 8; ++s) v += cp[((size_t)s * 64 + b) * 1024 + j];
    catw[(size_t)b * 1024 + j] = tanhf(v);
}

// ---------------------------------------------------------------------------
extern "C" void kernel_launch(void* const* d_in, const int* in_sizes, int n_in,
                              void* d_out, int out_size, void* d_ws, size_t ws_size,
                              hipStream_t stream) {
    const int*   seq  = (const int*)d_in[0];
    const float* h0   = (const float*)d_in[1];
    const float* enc  = (const float*)d_in[2];
    const int*   pos  = (const int*)d_in[3];
    const float* feat = (const float*)d_in[4];
    const float* emb  = (const float*)d_in[5];
    const float* pemb = (const float*)d_in[6];
    const float* W_ih = (const float*)d_in[7];
    const float* W_hh = (const float*)d_in[8];
    const float* b_ih = (const float*)d_in[9];
    const float* b_hh = (const float*)d_in[10];
    const float* W_c  = (const float*)d_in[11];
    const float* b_c  = (const float*)d_in[12];
    const float* W_o  = (const float*)d_in[13];
    const float* b_o  = (const float*)d_in[14];

    float* out = (float*)d_out;
    float* ws  = (float*)d_ws;

    float* x_ws     = ws;                // 64*2052          = 131328
    float* gx_part  = ws + 131328;       // 4*64*3072        = 786432
    float* gh_part  = ws + 917760;       // 4*64*3072        = 786432
    float* hc_ws    = ws + 1704192;      // 64*2048 (h|ctx)  = 131072
    float* e_ws     = ws + 1835264;      // 64*1024          = 65536
    float* part     = ws + 1900800;      // 64*16*1032       = 1056768
    float* cat_part = ws + 2957568;      // 8*64*1024        = 524288
    float* cat_ws   = ws + 3481856;      // 64*1024          = 65536

    build_x<<<64, 256, 0, stream>>>(seq, pos, feat, emb, pemb, x_ws);
    // W_ih: N=3072, K=2052, nk=65 -> 4 slices of 17
    gemm_bt<0, 0><<<dim3(48, 4), 256, 0, stream>>>(x_ws, W_ih, nullptr, gx_part,
                                                   3072, GRU_IN, 3072, 17);
    // W_hh: N=3072, K=1024, nk=32 -> 4 slices of 8
    gemm_bt<0, 0><<<dim3(48, 4), 256, 0, stream>>>(h0, W_hh, nullptr, gh_part,
                                                   3072, 1024, 3072, 8);
    gru_gates<<<256, 256, 0, stream>>>(gx_part, gh_part, b_ih, b_hh, h0, hc_ws,
                                       out + (size_t)Bdim * VOCAB);
    attn_pass<<<dim3(16, 64), 256, 0, stream>>>(enc, hc_ws, e_ws, part);
    attn_merge<<<64, 256, 0, stream>>>(part, e_ws, hc_ws, out);
    // W_c: N=1024, K=2048, nk=64 -> 8 slices of 8
    gemm_bt<0, 0><<<dim3(16, 8), 256, 0, stream>>>(hc_ws, W_c, nullptr, cat_part,
                                                   1024, 2048, 1024, 8);
    cat_combine<<<256, 256, 0, stream>>>(cat_part, b_c, cat_ws);
    // W_o: N=32000, K=1024, full-K, bias
    gemm_bt<0, 1><<<dim3(500, 1), 256, 0, stream>>>(cat_ws, W_o, b_o, out,
                                                    VOCAB, 1024, VOCAB, 32);
}